// Round 5
// baseline (94768.732 us; speedup 1.0000x reference)
//
#include <hip/hip_runtime.h>

// ======================= ws layout (bytes) — proven budget <= 76,558,336 =======================
static constexpr size_t OFF_ENC    = 0;          // bf16 [128 b][256 l][1024 f] = 64 MiB
// ---- enc-phase overlay ----
static constexpr size_t OFF_WGE    = 67108864;   // bf16 [2dir][2048 row][512 k]   (4 MiB)
static constexpr size_t OFF_WIHTE  = 71303168;   // bf16 [2dir][128 v][2048 row]   (1 MiB)
static constexpr size_t OFF_HENC   = 72351744;   // bf16 paired [(dir*2+par)][256 kk][128 b] (512 KiB)
static constexpr size_t OFF_CENC   = 72876032;   // f32  [2dir][512][128]          (512 KiB)
// ---- dec-phase overlay (pre2 phase runs after h0c0 phase; overwrites the above four) ----
static constexpr size_t OFF_WGATE  = 67108864;   // bf16 [2048 row][1024 k]        (4 MiB)
static constexpr size_t OFF_XDEC   = 71303168;   // bf16 [128 v][2048 row]         (512 KiB)
static constexpr size_t OFF_WATTT  = 71827456;   // bf16 [1024 i][512 o]           (1 MiB)
static constexpr size_t OFF_WOUT   = 72876032;   // bf16 [512 n][1536 k]           (1.5 MiB)
static constexpr size_t OFF_WVOCT  = 74448896;   // u32  [256 kk][128 v] bf16x2    (128 KiB)
// ---- persistent dec state ----
static constexpr size_t OFF_HDEC   = 74579968;   // bf16 paired [2 par][256 kk][128 b]
static constexpr size_t OFF_CDECP0 = 74842112;   // f32 [512][128]  (c parity 0; also c0 init)
static constexpr size_t OFF_TOUT   = 75104256;   // bf16 paired [2 par][256 kk][128 b]
static constexpr size_t OFF_UFB    = 75366400;   // bf16 paired [512 kk][128 b]
static constexpr size_t OFF_CDECP1 = 75628544;   // f32 [512][128]  (c parity 1)
static constexpr size_t OFF_CTXP   = 75890688;   // bf16 paired [2 ch][128 b][512 u32]
static constexpr size_t OFF_SC     = 76414976;   // bf16 [128 b][256 l]
static constexpr size_t OFF_MSP    = 76480512;   // f32 Mp[128][2], Sp at +1024
static constexpr size_t OFF_BAR    = 76483072;   // barrier state (8 KB)

// ======================= smem layout (bytes) =======================
static constexpr int SM_TILE = 0;        // 131072: 64 rows x 1024 bf16
static constexpr int SM_U    = 131072;   // 2048: u as 512 u32
static constexpr int SM_SCL  = 133120;   // 64 f32
static constexpr int SM_PL   = 133376;   // 64 f32
static constexpr int SM_RED  = 133632;   // 16 f32
static constexpr int SM_SIZE = 133696;

struct KP {
  const int* C_idx; const int* E_idx; const unsigned char* C_pad;
  const float* eWihF; const float* eWhhF; const float* ebF;
  const float* eWihB; const float* eWhhB; const float* ebB;
  const float* dWih;  const float* dWhh;  const float* db;
  const float* Wh; const float* Wc; const float* Wattn; const float* Wout; const float* Wvoc;
  const float* pgc; const float* pgi; const float* pgh; const float* pgcc; const float* pgb;
  char* wsb; float* out;
};

// ======================= helpers =======================
__device__ __forceinline__ float sigm(float x) { return 1.f / (1.f + expf(-x)); }
__device__ __forceinline__ unsigned short f2bf(float f) {
  unsigned u = __float_as_uint(f);
  u += 0x7fffu + ((u >> 16) & 1u);
  return (unsigned short)(u >> 16);
}
__device__ __forceinline__ float bfl(unsigned w) { return __uint_as_float(w << 16); }
__device__ __forceinline__ float bfh(unsigned w) { return __uint_as_float(w & 0xffff0000u); }
__device__ __forceinline__ float bf2f(unsigned short v) { return __uint_as_float(((unsigned)v) << 16); }

#if defined(__has_builtin)
#if __has_builtin(__builtin_amdgcn_fdot2_f32_bf16)
#define HAVE_DOT2BF 1
#endif
#endif
#ifdef HAVE_DOT2BF
typedef __bf16 bf2_t __attribute__((ext_vector_type(2)));
__device__ __forceinline__ float dot2bf(unsigned w, unsigned h, float acc) {
  return __builtin_amdgcn_fdot2_f32_bf16(__builtin_bit_cast(bf2_t, w),
                                         __builtin_bit_cast(bf2_t, h), acc, false);
}
#else
__device__ __forceinline__ float dot2bf(unsigned w, unsigned h, float acc) {
  return acc + bfl(w) * bfl(h) + bfh(w) * bfh(h);
}
#endif

// Grid barrier: RELAXED atomics + one release fence (entry) + one acquire fence (exit).
// Round-2 failure was ACQUIRE in the spin loop -> per-iteration L2 invalidate storm.
__device__ __forceinline__ void gbar(int* bar, int bid) {
  __syncthreads();
  if (threadIdx.x == 0) {
    __builtin_amdgcn_fence(__ATOMIC_RELEASE, "agent");       // push our writes to L3 once
    int* gen = bar + 32;
    int g = __hip_atomic_load(gen, __ATOMIC_RELAXED, __HIP_MEMORY_SCOPE_AGENT);
    int* gc = bar + 64 + (bid >> 4) * 32;
    if (__hip_atomic_fetch_add(gc, 1, __ATOMIC_RELAXED, __HIP_MEMORY_SCOPE_AGENT) == 15) {
      __hip_atomic_store(gc, 0, __ATOMIC_RELAXED, __HIP_MEMORY_SCOPE_AGENT);
      if (__hip_atomic_fetch_add(bar, 1, __ATOMIC_RELAXED, __HIP_MEMORY_SCOPE_AGENT) == 15) {
        __hip_atomic_store(bar, 0, __ATOMIC_RELAXED, __HIP_MEMORY_SCOPE_AGENT);
        __hip_atomic_store(gen, g + 1, __ATOMIC_RELEASE, __HIP_MEMORY_SCOPE_AGENT);
      }
    }
    while (__hip_atomic_load(gen, __ATOMIC_RELAXED, __HIP_MEMORY_SCOPE_AGENT) == g)
      __builtin_amdgcn_s_sleep(1);
    __builtin_amdgcn_fence(__ATOMIC_ACQUIRE, "agent");       // invalidate once on exit
  }
  __syncthreads();
}

// ======================= pre1 (separate kernel, before coop launch) =======================
__global__ __launch_bounds__(256) void k_pre1(const float* __restrict__ WhhF,
                                              const float* __restrict__ WhhB,
                                              const float* __restrict__ WihF,
                                              const float* __restrict__ WihB,
                                              char* __restrict__ wsb) {
  unsigned short* WGE = (unsigned short*)(wsb + OFF_WGE);
  unsigned short* WIH = (unsigned short*)(wsb + OFF_WIHTE);
  int id = blockIdx.x * 256 + threadIdx.x, str = gridDim.x * 256;
  for (int x = id; x < 2 * 2048 * 512; x += str) {
    int dir = x >> 20, r = (x >> 9) & 2047, k = x & 511;
    const float* W = dir ? WhhB : WhhF;
    WGE[x] = f2bf(W[(size_t)r * 512 + k]);
  }
  for (int x = id; x < 2 * 128 * 2048; x += str) {
    int dir = x >> 18, v = (x >> 11) & 127, r = x & 2047;
    const float* W = dir ? WihB : WihF;
    WIH[x] = f2bf(W[(size_t)r * 128 + v]);
  }
}

// ======================= phases =======================
__device__ void ph_enc(const KP& P, int bid, int tau, int t, float& c_enc) {
  char* wsb = P.wsb;
  int b = tau & 127, slot = tau >> 7;
  int dir = bid >> 7;
  int j = __builtin_amdgcn_readfirstlane(((bid & 127) << 2) + slot);
  int dd = __builtin_amdgcn_readfirstlane(dir);
  int rp = t & 1, wp = rp ^ 1;
  const unsigned* inw = (const unsigned*)(wsb + OFF_HENC) + (size_t)(dd * 2 + rp) * 32768 + b;
  const unsigned* WGE = (const unsigned*)(wsb + OFF_WGE);
  const uint4* w0 = (const uint4*)(WGE + ((size_t)dd * 2048 + j) * 256);
  const uint4* w1 = (const uint4*)(WGE + ((size_t)dd * 2048 + 512 + j) * 256);
  const uint4* w2 = (const uint4*)(WGE + ((size_t)dd * 2048 + 1024 + j) * 256);
  const uint4* w3 = (const uint4*)(WGE + ((size_t)dd * 2048 + 1536 + j) * 256);
  int l = dd ? (255 - t) : t;
  int cidx = P.C_idx[b * 256 + l];
  const unsigned short* xg = (const unsigned short*)(wsb + OFF_WIHTE) + ((size_t)dd * 128 + cidx) * 2048;
  const float* bias = dd ? P.ebB : P.ebF;
  float a0 = bias[j] + bf2f(xg[j]);
  float a1 = bias[512 + j] + bf2f(xg[512 + j]);
  float a2 = bias[1024 + j] + bf2f(xg[1024 + j]);
  float a3 = bias[1536 + j] + bf2f(xg[1536 + j]);
#pragma unroll 4
  for (int q = 0; q < 64; ++q) {
    uint4 W0 = w0[q], W1 = w1[q], W2 = w2[q], W3 = w3[q];
    unsigned i0 = inw[(q * 4 + 0) * 128], i1 = inw[(q * 4 + 1) * 128];
    unsigned i2 = inw[(q * 4 + 2) * 128], i3 = inw[(q * 4 + 3) * 128];
    a0 = dot2bf(W0.x, i0, a0); a0 = dot2bf(W0.y, i1, a0); a0 = dot2bf(W0.z, i2, a0); a0 = dot2bf(W0.w, i3, a0);
    a1 = dot2bf(W1.x, i0, a1); a1 = dot2bf(W1.y, i1, a1); a1 = dot2bf(W1.z, i2, a1); a1 = dot2bf(W1.w, i3, a1);
    a2 = dot2bf(W2.x, i0, a2); a2 = dot2bf(W2.y, i1, a2); a2 = dot2bf(W2.z, i2, a2); a2 = dot2bf(W2.w, i3, a2);
    a3 = dot2bf(W3.x, i0, a3); a3 = dot2bf(W3.y, i1, a3); a3 = dot2bf(W3.z, i2, a3); a3 = dot2bf(W3.w, i3, a3);
  }
  float ig = sigm(a0), fg = sigm(a1), gg = tanhf(a2), og = sigm(a3);
  float c = fg * c_enc + ig * gg;
  c_enc = c;
  float h = og * tanhf(c);
  unsigned short hb = f2bf(h);
  ((unsigned short*)(wsb + OFF_HENC))[(((size_t)(dir * 2 + wp) * 256 + (j >> 1)) * 128 + b) * 2 + (j & 1)] = hb;
  ((unsigned short*)(wsb + OFF_ENC))[((size_t)b * 256 + l) * 1024 + dir * 512 + j] = hb;
  if (t == 255) ((float*)(wsb + OFF_CENC))[((size_t)dir * 512 + j) * 128 + b] = c;
}

__device__ void ph_h0(const KP& P, int bid, int tau) {
  char* wsb = P.wsb;
  int b = tau & 127, slot = tau >> 7;
  int row = __builtin_amdgcn_readfirstlane(bid * 4 + slot);
  int sel = row >> 9, j = row & 511;
  const float* W = (sel ? P.Wc : P.Wh) + (size_t)j * 1024;
  const unsigned short* HE = (const unsigned short*)(wsb + OFF_HENC);
  const float* CE = (const float*)(wsb + OFF_CENC);
  float acc = 0.f;
  for (int k = 0; k < 1024; ++k) {
    int dir = k >> 9, k5 = k & 511;
    float in;
    if (sel == 0)
      in = bf2f(HE[(((size_t)(dir * 2 + 0) * 256 + (k5 >> 1)) * 128 + b) * 2 + (k5 & 1)]);
    else
      in = CE[((size_t)dir * 512 + k5) * 128 + b];
    acc += W[k] * in;
  }
  if (sel == 0)
    ((unsigned short*)(wsb + OFF_HDEC))[(((size_t)(j >> 1)) * 128 + b) * 2 + (j & 1)] = f2bf(acc);
  else
    ((float*)(wsb + OFF_CDECP0))[(size_t)j * 128 + b] = acc;
}

__device__ void ph_pre2(const KP& P, int bid, int tau) {
  char* wsb = P.wsb;
  unsigned short* WG = (unsigned short*)(wsb + OFF_WGATE);
  unsigned short* XD = (unsigned short*)(wsb + OFF_XDEC);
  unsigned short* WA = (unsigned short*)(wsb + OFF_WATTT);
  unsigned short* WO = (unsigned short*)(wsb + OFF_WOUT);
  unsigned*       WV = (unsigned*)(wsb + OFF_WVOCT);
  int id = bid * 512 + tau, str = 256 * 512;
  for (int x = id; x < 2048 * 1024; x += str) {
    int r = x >> 10, k = x & 1023;
    float v = (k < 512) ? P.dWih[(size_t)r * 640 + 128 + k] : P.dWhh[(size_t)r * 512 + (k - 512)];
    WG[x] = f2bf(v);
  }
  for (int x = id; x < 128 * 2048; x += str) {
    int v = x >> 11, r = x & 2047;
    XD[x] = f2bf(P.dWih[(size_t)r * 640 + v]);
  }
  for (int x = id; x < 1024 * 512; x += str) {
    int i = x >> 9, o = x & 511;
    WA[x] = f2bf(P.Wattn[(size_t)o * 1024 + i]);
  }
  for (int x = id; x < 512 * 1536; x += str) WO[x] = f2bf(P.Wout[x]);
  for (int x = id; x < 256 * 128; x += str) {
    int kk = x >> 7, v = x & 127;
    unsigned lo = f2bf(P.Wvoc[(size_t)v * 512 + 2 * kk]);
    unsigned hi = f2bf(P.Wvoc[(size_t)v * 512 + 2 * kk + 1]);
    WV[x] = lo | (hi << 16);
  }
}

__device__ void ph_gates(const KP& P, char* smem, int bid, int tau, int t, float& c_dec) {
  char* wsb = P.wsb;
  float (*part)[4][128] = (float(*)[4][128])smem;
  int b = tau & 127, jslot = (tau >> 7) & 1, kh = tau >> 8;
  int j = __builtin_amdgcn_readfirstlane(bid * 2 + jslot);
  int rp = t & 1, np = rp ^ 1;
  const unsigned* inw = (const unsigned*)(wsb + (kh ? OFF_HDEC : OFF_TOUT)) + (size_t)rp * 32768 + b;
  const unsigned* WG = (const unsigned*)(wsb + OFF_WGATE);
  const uint4* w0 = (const uint4*)(WG + (size_t)j * 512 + kh * 256);
  const uint4* w1 = (const uint4*)(WG + ((size_t)512 + j) * 512 + kh * 256);
  const uint4* w2 = (const uint4*)(WG + ((size_t)1024 + j) * 512 + kh * 256);
  const uint4* w3 = (const uint4*)(WG + ((size_t)1536 + j) * 512 + kh * 256);
  float a0 = 0.f, a1 = 0.f, a2 = 0.f, a3 = 0.f;
#pragma unroll 4
  for (int q = 0; q < 64; ++q) {
    uint4 W0 = w0[q], W1 = w1[q], W2 = w2[q], W3 = w3[q];
    unsigned i0 = inw[(q * 4 + 0) * 128], i1 = inw[(q * 4 + 1) * 128];
    unsigned i2 = inw[(q * 4 + 2) * 128], i3 = inw[(q * 4 + 3) * 128];
    a0 = dot2bf(W0.x, i0, a0); a0 = dot2bf(W0.y, i1, a0); a0 = dot2bf(W0.z, i2, a0); a0 = dot2bf(W0.w, i3, a0);
    a1 = dot2bf(W1.x, i0, a1); a1 = dot2bf(W1.y, i1, a1); a1 = dot2bf(W1.z, i2, a1); a1 = dot2bf(W1.w, i3, a1);
    a2 = dot2bf(W2.x, i0, a2); a2 = dot2bf(W2.y, i1, a2); a2 = dot2bf(W2.z, i2, a2); a2 = dot2bf(W2.w, i3, a2);
    a3 = dot2bf(W3.x, i0, a3); a3 = dot2bf(W3.y, i1, a3); a3 = dot2bf(W3.z, i2, a3); a3 = dot2bf(W3.w, i3, a3);
  }
  if (kh == 1) { part[jslot][0][b] = a0; part[jslot][1][b] = a1; part[jslot][2][b] = a2; part[jslot][3][b] = a3; }
  __syncthreads();
  if (kh == 0) {
    if (t == 0) c_dec = ((const float*)(wsb + OFF_CDECP0))[(size_t)j * 128 + b];
    int xid = P.E_idx[b * 257 + t];
    const unsigned short* xg = (const unsigned short*)(wsb + OFF_XDEC) + (size_t)xid * 2048;
    float g0 = a0 + part[jslot][0][b] + P.db[j] + bf2f(xg[j]);
    float g1 = a1 + part[jslot][1][b] + P.db[512 + j] + bf2f(xg[512 + j]);
    float g2 = a2 + part[jslot][2][b] + P.db[1024 + j] + bf2f(xg[1024 + j]);
    float g3 = a3 + part[jslot][3][b] + P.db[1536 + j] + bf2f(xg[1536 + j]);
    float ig = sigm(g0), fg = sigm(g1), gg = tanhf(g2), og = sigm(g3);
    float c = fg * c_dec + ig * gg;
    c_dec = c;
    float h = og * tanhf(c);
    ((float*)(wsb + (np ? OFF_CDECP1 : OFF_CDECP0)))[(size_t)j * 128 + b] = c;
    ((unsigned short*)(wsb + OFF_HDEC))[(((size_t)np * 256 + (j >> 1)) * 128 + b) * 2 + (j & 1)] = f2bf(h);
  }
  __syncthreads();
}

__device__ void ph_u(const KP& P, int bid, int tau, int t) {
  char* wsb = P.wsb;
  int b = tau & 127, rslot = tau >> 7;
  int i0 = __builtin_amdgcn_readfirstlane(bid * 8 + rslot * 2);
  int np = (t & 1) ^ 1;
  const unsigned* inw = (const unsigned*)(wsb + OFF_HDEC) + (size_t)np * 32768 + b;
  float aa[2];
#pragma unroll
  for (int r = 0; r < 2; ++r) {
    const uint4* w = (const uint4*)((const unsigned*)(wsb + OFF_WATTT) + (size_t)(i0 + r) * 256);
    float a = 0.f;
#pragma unroll 4
    for (int q = 0; q < 64; ++q) {
      uint4 W = w[q];
      a = dot2bf(W.x, inw[(q * 4 + 0) * 128], a);
      a = dot2bf(W.y, inw[(q * 4 + 1) * 128], a);
      a = dot2bf(W.z, inw[(q * 4 + 2) * 128], a);
      a = dot2bf(W.w, inw[(q * 4 + 3) * 128], a);
    }
    aa[r] = a;
  }
  ((unsigned*)(wsb + OFF_UFB))[((size_t)(i0 >> 1)) * 128 + b] =
      (unsigned)f2bf(aa[0]) | ((unsigned)f2bf(aa[1]) << 16);
}

__device__ void ph_attn(const KP& P, char* smem, int bid, int tau, int t) {
  char* wsb = P.wsb;
  uint4* tile4 = (uint4*)(smem + SM_TILE);
  const unsigned* tl = (const unsigned*)(smem + SM_TILE);
  unsigned* ulds = (unsigned*)(smem + SM_U);
  float* sc_l = (float*)(smem + SM_SCL);
  float* p_l = (float*)(smem + SM_PL);
  float* red = (float*)(smem + SM_RED);
  int b = bid >> 1, ch = bid & 1;
  int lane = tau & 63, wv = tau >> 6;
  const unsigned* UW = (const unsigned*)(wsb + OFF_UFB) + b;
  ulds[tau] = UW[(size_t)tau * 128];
  float mold = -3.0e38f, ssum = 0.f, acc0 = 0.f, acc1 = 0.f;
  unsigned short* SCp = (unsigned short*)(wsb + OFF_SC) + (size_t)b * 256;
  int L0 = ch * 128;
  for (int sub = 0; sub < 2; ++sub) {
    const uint4* src = (const uint4*)((const unsigned short*)wsb + ((size_t)b * 256 + L0 + sub * 64) * 1024);
    __syncthreads();
#pragma unroll
    for (int it = 0; it < 16; ++it) tile4[it * 512 + tau] = src[it * 512 + tau];
    __syncthreads();
    const uint4* u4 = (const uint4*)ulds;
    uint4 ua = u4[lane * 2], ub = u4[lane * 2 + 1];
#pragma unroll
    for (int li = 0; li < 8; ++li) {
      int l = wv * 8 + li;
      uint4 ea = tile4[l * 128 + lane * 2];
      uint4 eb = tile4[l * 128 + lane * 2 + 1];
      float s = 0.f;
      s = dot2bf(ea.x, ua.x, s); s = dot2bf(ea.y, ua.y, s);
      s = dot2bf(ea.z, ua.z, s); s = dot2bf(ea.w, ua.w, s);
      s = dot2bf(eb.x, ub.x, s); s = dot2bf(eb.y, ub.y, s);
      s = dot2bf(eb.z, ub.z, s); s = dot2bf(eb.w, ub.w, s);
      for (int o = 32; o; o >>= 1) s += __shfl_xor(s, o);
      if (lane == 0) {
        int gl = L0 + sub * 64 + l;
        if (P.C_pad[b * 256 + gl]) s = -3.0e38f;
        sc_l[l] = s;
        SCp[gl] = f2bf(s);
      }
    }
    __syncthreads();
    if (tau < 64) {
      float v = sc_l[tau];
      for (int o = 32; o; o >>= 1) v = fmaxf(v, __shfl_xor(v, o));
      if (tau == 0) red[0] = v;
    }
    __syncthreads();
    float mnew = fmaxf(mold, red[0]);
    float r = expf(mold - mnew);
    if (tau < 64) {
      float pv = expf(sc_l[tau] - mnew);
      p_l[tau] = pv;
      for (int o = 32; o; o >>= 1) pv += __shfl_xor(pv, o);
      if (tau == 0) red[1] = pv;
    }
    __syncthreads();
    ssum = ssum * r + red[1];
    mold = mnew;
    acc0 *= r; acc1 *= r;
#pragma unroll 8
    for (int l = 0; l < 64; ++l) {
      float pv = p_l[l];
      unsigned ev = tl[l * 512 + tau];
      acc0 += pv * bfl(ev); acc1 += pv * bfh(ev);
    }
  }
  ((unsigned*)(wsb + OFF_CTXP))[((size_t)ch * 128 + b) * 512 + tau] =
      (unsigned)f2bf(acc0) | ((unsigned)f2bf(acc1) << 16);
  if (tau == 0) {
    float* MSP = (float*)(wsb + OFF_MSP);
    MSP[b * 2 + ch] = mold;
    MSP[256 + b * 2 + ch] = ssum;
  }
  __syncthreads();
}

__device__ void ph_wout(const KP& P, char* smem, int bid, int tau, int t) {
  char* wsb = P.wsb;
  float (*part)[128] = (float(*)[128])smem;
  int b = tau & 127, nslot = (tau >> 7) & 1, kh = tau >> 8;
  int n = __builtin_amdgcn_readfirstlane(bid * 2 + nslot);
  int np = (t & 1) ^ 1;
  const float* MSP = (const float*)(wsb + OFF_MSP);
  float m0 = MSP[b * 2], m1 = MSP[b * 2 + 1];
  float s0 = MSP[256 + b * 2], s1 = MSP[256 + b * 2 + 1];
  float M = fmaxf(m0, m1);
  float e0 = expf(m0 - M), e1 = expf(m1 - M);
  float invD = 1.f / (s0 * e0 + s1 * e1);
  e0 *= invD; e1 *= invD;
  const unsigned* HW = (const unsigned*)(wsb + OFF_HDEC) + (size_t)np * 32768 + b;
  const unsigned* CP0 = (const unsigned*)(wsb + OFF_CTXP) + (size_t)b * 512;
  const unsigned* CP1 = CP0 + 65536;
  const unsigned* w = (const unsigned*)(wsb + OFF_WOUT) + (size_t)n * 768 + kh * 384;
  float a = 0.f;
  int p0 = kh * 384;
#pragma unroll 4
  for (int q = 0; q < 96; ++q) {
    uint4 W = ((const uint4*)w)[q];
#pragma unroll
    for (int e = 0; e < 4; ++e) {
      int pp = p0 + q * 4 + e;
      unsigned wvv = (e == 0) ? W.x : (e == 1) ? W.y : (e == 2) ? W.z : W.w;
      if (pp < 256) {
        a = dot2bf(wvv, HW[(size_t)pp * 128], a);
      } else {
        int ci = pp - 256;
        unsigned c0 = CP0[ci], c1 = CP1[ci];
        float x0 = bfl(c0) * e0 + bfl(c1) * e1;
        float x1 = bfh(c0) * e0 + bfh(c1) * e1;
        a += bfl(wvv) * x0 + bfh(wvv) * x1;
      }
    }
  }
  if (kh == 1) part[nslot][b] = a;
  __syncthreads();
  if (kh == 0) {
    float tv = tanhf(a + part[nslot][b]);
    ((unsigned short*)(wsb + OFF_TOUT))[(((size_t)np * 256 + (n >> 1)) * 128 + b) * 2 + (n & 1)] = f2bf(tv);
  }
  __syncthreads();
}

// fin(tf): vocab softmax at target + pgen + copy mass + nll. Runs on 512 threads.
__device__ void ph_fin(const KP& P, char* smem, int b, int tf) {
  char* wsb = P.wsb;
  unsigned* to_pld = (unsigned*)smem;            // 256 u32
  float* lgp = (float*)(smem + 1024);            // [4][128]
  float* lgf = (float*)(smem + 3072);            // 128
  float* red = (float*)(smem + 3584);            // 16
  int tau = threadIdx.x, lane = tau & 63, wv = tau >> 6;
  int npf = (tf & 1) ^ 1, rpf = tf & 1;
  const unsigned* TOW = (const unsigned*)(wsb + OFF_TOUT) + (size_t)npf * 32768 + b;
  if (tau < 256) to_pld[tau] = TOW[(size_t)tau * 128];
  __syncthreads();
  int v = tau & 127, kh = tau >> 7;
  const unsigned* WV = (const unsigned*)(wsb + OFF_WVOCT) + v;
  float a = 0.f;
#pragma unroll 8
  for (int q = 0; q < 64; ++q) {
    int kk = kh * 64 + q;
    a = dot2bf(WV[(size_t)kk * 128], to_pld[kk], a);
  }
  lgp[kh * 128 + v] = a;
  __syncthreads();
  if (tau < 128) {
    float lg = lgp[tau] + lgp[128 + tau] + lgp[256 + tau] + lgp[384 + tau];
    lgf[tau] = lg;
    float m = lg;
    for (int o = 32; o; o >>= 1) m = fmaxf(m, __shfl_xor(m, o));
    if (lane == 0) red[wv] = m;
  }
  __syncthreads();
  float mx = fmaxf(red[0], red[1]);
  if (tau < 128) {
    float e = expf(lgf[tau] - mx);
    for (int o = 32; o; o >>= 1) e += __shfl_xor(e, o);
    if (lane == 0) red[2 + wv] = e;
  }
  const float* MSP = (const float*)(wsb + OFF_MSP);
  float m0 = MSP[b * 2], m1 = MSP[b * 2 + 1];
  float s0 = MSP[256 + b * 2], s1 = MSP[256 + b * 2 + 1];
  float M = fmaxf(m0, m1);
  float e0 = expf(m0 - M), e1 = expf(m1 - M);
  float invD = 1.f / (s0 * e0 + s1 * e1);
  int tgt = P.E_idx[b * 257 + tf + 1];
  float cm = 0.f;
  if (tau < 256) {
    float s = bf2f(((const unsigned short*)(wsb + OFF_SC))[(size_t)b * 256 + tau]);
    if (P.C_idx[b * 256 + tau] == tgt) cm = expf(s - M);
  }
  for (int o = 32; o; o >>= 1) cm += __shfl_xor(cm, o);
  if (lane == 0 && wv < 4) red[4 + wv] = cm;
  // pgen partial: 2 ctx features + 1 (h,c,prev_out) feature per thread
  const unsigned* CP0 = (const unsigned*)(wsb + OFF_CTXP) + (size_t)b * 512;
  const unsigned* CP1 = CP0 + 65536;
  unsigned c0 = CP0[tau], c1 = CP1[tau];
  float x0 = (bfl(c0) * e0 + bfl(c1) * e1) * invD;
  float x1 = (bfh(c0) * e0 + bfh(c1) * e1) * invD;
  float pp = x0 * P.pgc[2 * tau] + x1 * P.pgc[2 * tau + 1];
  {
    int f = tau;
    const unsigned short* H = (const unsigned short*)(wsb + OFF_HDEC) + (size_t)npf * 65536;
    const unsigned short* TOp = (const unsigned short*)(wsb + OFF_TOUT) + (size_t)rpf * 65536;
    const float* C = (const float*)(wsb + (npf ? OFF_CDECP1 : OFF_CDECP0));
    float hv = bf2f(H[((size_t)(f >> 1) * 128 + b) * 2 + (f & 1)]);
    float tv = bf2f(TOp[((size_t)(f >> 1) * 128 + b) * 2 + (f & 1)]);
    float cv = C[(size_t)f * 128 + b];
    pp += hv * P.pgh[f] + cv * P.pgcc[f] + tv * P.pgi[128 + f];
  }
  for (int o = 32; o; o >>= 1) pp += __shfl_xor(pp, o);
  if (lane == 0) red[8 + wv] = pp;
  __syncthreads();
  if (tau == 0) {
    float sume = red[2] + red[3];
    float copy_raw = (red[4] + red[5] + red[6] + red[7]) * invD;
    float pgs = red[8] + red[9] + red[10] + red[11] + red[12] + red[13] + red[14] + red[15];
    pgs += P.pgi[P.E_idx[b * 257 + tf]] + P.pgb[0];
    float pg = sigm(pgs);
    float gen_tgt = expf(lgf[tgt] - mx) / sume;
    float prob = pg * gen_tgt + (1.f - pg) * copy_raw;
    P.out[b * 256 + tf] = (tgt == 0) ? 0.f : -logf(prob);
  }
  __syncthreads();
}

// ======================= the persistent kernel =======================
__global__ void __launch_bounds__(512) k_all(KP P) {
  __shared__ __align__(16) char smem[SM_SIZE];
  const int bid = blockIdx.x;
  const int tau = threadIdx.x;
  int* bar = (int*)(P.wsb + OFF_BAR);
  float c_enc = 0.f, c_dec = 0.f;

  for (int t = 0; t < 256; ++t) { ph_enc(P, bid, tau, t, c_enc); gbar(bar, bid); }
  ph_h0(P, bid, tau);
  gbar(bar, bid);
  ph_pre2(P, bid, tau);
  gbar(bar, bid);
  for (int t = 0; t < 256; ++t) {
    ph_gates(P, smem, bid, tau, t, c_dec);
    gbar(bar, bid);
    if (bid < 128) ph_u(P, bid, tau, t);
    else if (t > 0) ph_fin(P, smem, bid - 128, t - 1);
    gbar(bar, bid);
    ph_attn(P, smem, bid, tau, t);
    gbar(bar, bid);
    ph_wout(P, smem, bid, tau, t);
    gbar(bar, bid);
  }
  if (bid >= 128) ph_fin(P, smem, bid - 128, 255);
}

// ======================= host =======================
extern "C" void kernel_launch(void* const* d_in, const int* in_sizes, int n_in,
                              void* d_out, int out_size, void* d_ws, size_t ws_size,
                              hipStream_t stream) {
  (void)in_sizes; (void)n_in; (void)out_size; (void)ws_size;
  KP P;
  P.C_idx = (const int*)d_in[0];
  P.E_idx = (const int*)d_in[1];
  P.C_pad = (const unsigned char*)d_in[2];
  P.eWihF = (const float*)d_in[3];
  P.eWhhF = (const float*)d_in[4];
  P.ebF   = (const float*)d_in[5];
  P.eWihB = (const float*)d_in[6];
  P.eWhhB = (const float*)d_in[7];
  P.ebB   = (const float*)d_in[8];
  P.dWih  = (const float*)d_in[9];
  P.dWhh  = (const float*)d_in[10];
  P.db    = (const float*)d_in[11];
  P.Wh    = (const float*)d_in[12];
  P.Wc    = (const float*)d_in[13];
  P.Wattn = (const float*)d_in[14];
  P.Wout  = (const float*)d_in[15];
  P.Wvoc  = (const float*)d_in[16];
  P.pgc   = (const float*)d_in[17];
  P.pgi   = (const float*)d_in[18];
  P.pgh   = (const float*)d_in[19];
  P.pgcc  = (const float*)d_in[20];
  P.pgb   = (const float*)d_in[21];
  P.wsb   = (char*)d_ws;
  P.out   = (float*)d_out;

  hipMemsetAsync((char*)d_ws + OFF_HENC, 0, 524288, stream);  // enc h planes (both dirs/parities)
  hipMemsetAsync((char*)d_ws + OFF_TOUT, 0, 262144, stream);  // prev_out both parities
  hipMemsetAsync((char*)d_ws + OFF_BAR, 0, 8192, stream);     // barrier state

  k_pre1<<<256, 256, 0, stream>>>(P.eWhhF, P.eWhhB, P.eWihF, P.eWihB, P.wsb);

  void* args[] = { &P };
  hipLaunchCooperativeKernel((const void*)k_all, dim3(256), dim3(512), args, 0, stream);
}

// Round 6
// 69803.180 us; speedup vs baseline: 1.3577x; 1.3577x over previous
//
#include <hip/hip_runtime.h>

// ======================= ws layout (bytes) — high-water 76,484,096 (< proven 76,491,264) ===
static constexpr size_t OFF_ENC   = 0;          // bf16 [128 b][256 l][1024 f] = 64 MiB
// enc-phase aliases (dead after k_h0):
static constexpr size_t OFF_HFIN  = 67108864;   // f32 [128 b][2 dir][512]  (512 KiB)
static constexpr size_t OFF_CFIN  = 67633152;   // f32 [128 b][2 dir][512]  (512 KiB)
// dec-phase state in the same region:
static constexpr size_t OFF_TOUT  = 67108864;   // bf16 paired [2 par][256 kk][128 b] (512 KiB)
static constexpr size_t OFF_CTXP  = 67633152;   // u32 [2 ch][128 b][512]   (512 KiB)
// overlay (enc weights, then dec weights):
static constexpr size_t OFF_OVL   = 68157440;   // enc: WHHE 4MiB + WIHT 1MiB
static constexpr size_t OFF_WGATE = 68157440;   // bf16 [2048 row][1024 k]  (4 MiB)
static constexpr size_t OFF_XDEC  = 72351744;   // bf16 [128 v][2048 row]   (512 KiB)
static constexpr size_t OFF_WATTT = 72876032;   // bf16 [1024 i][512 o]     (1 MiB)
static constexpr size_t OFF_WOUT  = 73924608;   // bf16 [512 n][1536 k]     (1.5 MiB)
static constexpr size_t OFF_WVOCT = 75497472;   // u32 [256 kk][128 v]      (128 KiB)
// persistent dec state:
static constexpr size_t OFF_HDEC  = 75628544;   // bf16 paired [2 par][256 kk][128 b] (256 KiB)
static constexpr size_t OFF_CDEC  = 75890688;   // f32 [512][128]           (256 KiB, single plane RMW)
static constexpr size_t OFF_UFB   = 76152832;   // bf16 paired [512 kk][128 b] (256 KiB)
static constexpr size_t OFF_SC    = 76414976;   // bf16 [128 b][256 l]      (64 KiB)
static constexpr size_t OFF_MSP   = 76480512;   // f32 m[128][2]; s[128][2] at +1024
static constexpr size_t OFF_MD    = 76482560;   // f32 M[128], D[128], PG[128]

// ======================= helpers =======================
__device__ __forceinline__ float sigm(float x) { return 1.f / (1.f + expf(-x)); }
__device__ __forceinline__ unsigned short f2bf(float f) {
  unsigned u = __float_as_uint(f);
  u += 0x7fffu + ((u >> 16) & 1u);
  return (unsigned short)(u >> 16);
}
__device__ __forceinline__ float bfl(unsigned w) { return __uint_as_float(w << 16); }
__device__ __forceinline__ float bfh(unsigned w) { return __uint_as_float(w & 0xffff0000u); }
__device__ __forceinline__ float bf2f(unsigned short v) { return __uint_as_float(((unsigned)v) << 16); }

#if defined(__has_builtin)
#if __has_builtin(__builtin_amdgcn_fdot2_f32_bf16)
#define HAVE_DOT2BF 1
#endif
#endif
#ifdef HAVE_DOT2BF
typedef __bf16 bf2_t __attribute__((ext_vector_type(2)));
__device__ __forceinline__ float dot2bf(unsigned w, unsigned h, float acc) {
  return __builtin_amdgcn_fdot2_f32_bf16(__builtin_bit_cast(bf2_t, w),
                                         __builtin_bit_cast(bf2_t, h), acc, false);
}
#else
__device__ __forceinline__ float dot2bf(unsigned w, unsigned h, float acc) {
  return acc + bfl(w) * bfl(h) + bfh(w) * bfh(h);
}
#endif

// ======================= pre1: encoder weight packing (round-3, proven) =======================
__global__ __launch_bounds__(256) void k_pre1(const float* __restrict__ WhhF,
                                              const float* __restrict__ WhhB,
                                              const float* __restrict__ WihF,
                                              const float* __restrict__ WihB,
                                              char* __restrict__ wsb) {
  unsigned short* dst = (unsigned short*)(wsb + OFF_OVL);
  int id = blockIdx.x * 256 + threadIdx.x, str = gridDim.x * 256;
  for (int x = id; x < 2097152; x += str) {           // WHHE [dir][k2][j][8]
    int dir = x >> 20, r = x & 1048575;
    int e = r & 7, j = (r >> 3) & 511, k2 = r >> 12;
    int g = e >> 1, k = k2 * 2 + (e & 1);
    const float* W = dir ? WhhB : WhhF;
    dst[x] = f2bf(W[((size_t)g * 512 + j) * 512 + k]);
  }
  for (int x = id; x < 524288; x += str) {            // WIHT [dir][v][j][4]
    int dir = x >> 18, r = x & 262143;
    int g = r & 3, j = (r >> 2) & 511, v = r >> 11;
    const float* W = dir ? WihB : WihF;
    dst[2097152 + x] = f2bf(W[((size_t)g * 512 + j) * 128 + v]);
  }
}

// ======================= encoder: one block per (b, dir), all 256 steps (round-3, proven) ====
__global__ __launch_bounds__(512) void k_enc(const float* __restrict__ bF,
                                             const float* __restrict__ bB,
                                             const int* __restrict__ C_idx,
                                             char* __restrict__ wsb) {
  __shared__ __align__(16) unsigned short hbf[512];
  int bid = blockIdx.x;
  int b = bid & 127, dir = bid >> 7;
  int j = threadIdx.x;
  const unsigned short* WH = (const unsigned short*)(wsb + OFF_OVL) + (size_t)dir * 1048576;
  const unsigned short* WX = (const unsigned short*)(wsb + OFF_OVL) + 2097152 + (size_t)dir * 262144;
  const float* bias = dir ? bB : bF;
  float b0 = bias[j], b1 = bias[512 + j], b2 = bias[1024 + j], b3 = bias[1536 + j];
  unsigned short* encb = (unsigned short*)wsb + (size_t)b * 262144;
  const uint4* wp = (const uint4*)WH + j;
  float c = 0.f, h = 0.f;
  hbf[j] = 0;
  __syncthreads();
  for (int t = 0; t < 256; ++t) {
    int l = dir ? (255 - t) : t;
    int cidx = C_idx[b * 256 + l];
    uint2 xg = *(const uint2*)(WX + ((size_t)cidx * 512 + j) * 4);
    float a0 = b0 + bfl(xg.x), a1 = b1 + bfh(xg.x);
    float a2 = b2 + bfl(xg.y), a3 = b3 + bfh(xg.y);
    for (int k2 = 0; k2 < 256; ++k2) {
      uint4 w = wp[(size_t)k2 * 512];
      unsigned hp = *(const unsigned*)((const char*)hbf + k2 * 4);
      a0 = dot2bf(w.x, hp, a0);
      a1 = dot2bf(w.y, hp, a1);
      a2 = dot2bf(w.z, hp, a2);
      a3 = dot2bf(w.w, hp, a3);
    }
    float ig = sigm(a0), fg = sigm(a1), gg = tanhf(a2), og = sigm(a3);
    c = fg * c + ig * gg;
    h = og * tanhf(c);
    __syncthreads();
    unsigned short hb = f2bf(h);
    hbf[j] = hb;
    encb[(size_t)l * 1024 + dir * 512 + j] = hb;
    __syncthreads();
  }
  ((float*)(wsb + OFF_HFIN))[((size_t)b * 2 + dir) * 512 + j] = h;
  ((float*)(wsb + OFF_CFIN))[((size_t)b * 2 + dir) * 512 + j] = c;
}

// ======================= h0/c0: grid 256 x 512 =======================
__global__ __launch_bounds__(512) void k_h0(const float* __restrict__ Wh,
                                            const float* __restrict__ Wc,
                                            char* __restrict__ wsb) {
  int tau = threadIdx.x;
  int b = tau & 127, slot = tau >> 7;
  int row = __builtin_amdgcn_readfirstlane(blockIdx.x * 4 + slot);
  int sel = row >> 9, j = row & 511;
  const float* W = (sel ? Wc : Wh) + (size_t)j * 1024;
  const float* IN = (const float*)(wsb + (sel ? OFF_CFIN : OFF_HFIN)) + (size_t)b * 1024;
  float acc = 0.f;
  for (int k = 0; k < 1024; k += 4) {
    float4 wf = *(const float4*)(W + k);
    acc += wf.x * IN[k] + wf.y * IN[k + 1] + wf.z * IN[k + 2] + wf.w * IN[k + 3];
  }
  if (sel == 0)
    ((unsigned short*)(wsb + OFF_HDEC))[((size_t)(j >> 1) * 128 + b) * 2 + (j & 1)] = f2bf(acc);
  else
    ((float*)(wsb + OFF_CDEC))[(size_t)j * 128 + b] = acc;
}

// ======================= pre2: decoder weight packing =======================
__global__ __launch_bounds__(256) void k_pre2(const float* __restrict__ dWih,
                                              const float* __restrict__ dWhh,
                                              const float* __restrict__ Wattn,
                                              const float* __restrict__ Wout,
                                              const float* __restrict__ Wvoc,
                                              char* __restrict__ wsb) {
  unsigned short* WG = (unsigned short*)(wsb + OFF_WGATE);
  unsigned short* XD = (unsigned short*)(wsb + OFF_XDEC);
  unsigned short* WA = (unsigned short*)(wsb + OFF_WATTT);
  unsigned short* WO = (unsigned short*)(wsb + OFF_WOUT);
  unsigned*       WV = (unsigned*)(wsb + OFF_WVOCT);
  int id = blockIdx.x * 256 + threadIdx.x, str = gridDim.x * 256;
  for (int x = id; x < 2048 * 1024; x += str) {
    int r = x >> 10, k = x & 1023;
    float v = (k < 512) ? dWih[(size_t)r * 640 + 128 + k] : dWhh[(size_t)r * 512 + (k - 512)];
    WG[x] = f2bf(v);
  }
  for (int x = id; x < 128 * 2048; x += str) {
    int v = x >> 11, r = x & 2047;
    XD[x] = f2bf(dWih[(size_t)r * 640 + v]);
  }
  for (int x = id; x < 1024 * 512; x += str) {
    int i = x >> 9, o = x & 511;
    WA[x] = f2bf(Wattn[(size_t)o * 1024 + i]);
  }
  for (int x = id; x < 512 * 1536; x += str) WO[x] = f2bf(Wout[x]);
  for (int x = id; x < 256 * 128; x += str) {
    int kk = x >> 7, v = x & 127;
    unsigned lo = f2bf(Wvoc[(size_t)v * 512 + 2 * kk]);
    unsigned hi = f2bf(Wvoc[(size_t)v * 512 + 2 * kk + 1]);
    WV[x] = lo | (hi << 16);
  }
}

// ======================= fin body (512 threads): vocab softmax + copy mass + nll ============
__device__ void fin_body(const int* __restrict__ C_idx, const int* __restrict__ E_idx,
                         char* __restrict__ wsb, float* __restrict__ out, int b, int tf) {
  __shared__ unsigned to_pld[256];
  __shared__ float lgp[4][128];
  __shared__ float lgf[128];
  __shared__ float redf[8];
  int tau = threadIdx.x, lane = tau & 63, wv = tau >> 6;
  int npf = (tf & 1) ^ 1;
  const unsigned* TOW = (const unsigned*)(wsb + OFF_TOUT) + (size_t)npf * 32768 + b;
  if (tau < 256) to_pld[tau] = TOW[(size_t)tau * 128];
  __syncthreads();
  int v = tau & 127, kh = tau >> 7;   // kh 0..3, 64 kk each
  const unsigned* WV = (const unsigned*)(wsb + OFF_WVOCT) + v;
  float a = 0.f;
#pragma unroll 8
  for (int q = 0; q < 64; ++q) {
    int kk = kh * 64 + q;
    a = dot2bf(WV[(size_t)kk * 128], to_pld[kk], a);
  }
  lgp[kh][v] = a;
  __syncthreads();
  if (tau < 128) {
    float lg = lgp[0][tau] + lgp[1][tau] + lgp[2][tau] + lgp[3][tau];
    lgf[tau] = lg;
    float m = lg;
    for (int o = 32; o; o >>= 1) m = fmaxf(m, __shfl_xor(m, o));
    if (lane == 0) redf[wv] = m;
  }
  __syncthreads();
  float mx = fmaxf(redf[0], redf[1]);
  if (tau < 128) {
    float e = expf(lgf[tau] - mx);
    for (int o = 32; o; o >>= 1) e += __shfl_xor(e, o);
    if (lane == 0) redf[2 + wv] = e;
  }
  const float* MD = (const float*)(wsb + OFF_MD);
  float M = MD[b], D = MD[128 + b], pg = MD[256 + b];
  int tgt = E_idx[b * 257 + tf + 1];
  float cm = 0.f;
  if (tau < 256) {
    float s = bf2f(((const unsigned short*)(wsb + OFF_SC))[(size_t)b * 256 + tau]);
    if (C_idx[b * 256 + tau] == tgt) cm = expf(s - M);
  }
  for (int o = 32; o; o >>= 1) cm += __shfl_xor(cm, o);
  if (lane == 0 && wv < 4) redf[4 + wv] = cm;
  __syncthreads();
  if (tau == 0) {
    float sume = redf[2] + redf[3];
    float copy_raw = (redf[4] + redf[5] + redf[6] + redf[7]) / D;
    float gen_tgt = expf(lgf[tgt] - mx) / sume;
    float prob = pg * gen_tgt + (1.f - pg) * copy_raw;
    out[b * 256 + tf] = (tgt == 0) ? 0.f : -logf(prob);
  }
}

// ======================= K1: gates (blocks 0-255) + fin(t-1) (blocks 256-383) ===============
__global__ __launch_bounds__(512) void k_gfin(const int* __restrict__ C_idx,
                                              const int* __restrict__ E_idx,
                                              const float* __restrict__ db,
                                              char* __restrict__ wsb,
                                              float* __restrict__ out, int t) {
  if (blockIdx.x >= 256) {
    if (t > 0) fin_body(C_idx, E_idx, wsb, out, blockIdx.x - 256, t - 1);
    return;
  }
  __shared__ float part[2][4][128];
  int tau = threadIdx.x;
  int b = tau & 127, jslot = (tau >> 7) & 1, kh = tau >> 8;
  int j = __builtin_amdgcn_readfirstlane(blockIdx.x * 2 + jslot);
  int rp = t & 1, np = rp ^ 1;
  const unsigned* inw = (const unsigned*)(wsb + (kh ? OFF_HDEC : OFF_TOUT)) + (size_t)rp * 32768 + b;
  const unsigned* WG = (const unsigned*)(wsb + OFF_WGATE);
  const uint4* w0 = (const uint4*)(WG + (size_t)j * 512 + kh * 256);
  const uint4* w1 = (const uint4*)(WG + ((size_t)512 + j) * 512 + kh * 256);
  const uint4* w2 = (const uint4*)(WG + ((size_t)1024 + j) * 512 + kh * 256);
  const uint4* w3 = (const uint4*)(WG + ((size_t)1536 + j) * 512 + kh * 256);
  float a0 = 0.f, a1 = 0.f, a2 = 0.f, a3 = 0.f;
#pragma unroll 4
  for (int q = 0; q < 64; ++q) {
    uint4 W0 = w0[q], W1 = w1[q], W2 = w2[q], W3 = w3[q];
    unsigned i0 = inw[(q * 4 + 0) * 128], i1 = inw[(q * 4 + 1) * 128];
    unsigned i2 = inw[(q * 4 + 2) * 128], i3 = inw[(q * 4 + 3) * 128];
    a0 = dot2bf(W0.x, i0, a0); a0 = dot2bf(W0.y, i1, a0); a0 = dot2bf(W0.z, i2, a0); a0 = dot2bf(W0.w, i3, a0);
    a1 = dot2bf(W1.x, i0, a1); a1 = dot2bf(W1.y, i1, a1); a1 = dot2bf(W1.z, i2, a1); a1 = dot2bf(W1.w, i3, a1);
    a2 = dot2bf(W2.x, i0, a2); a2 = dot2bf(W2.y, i1, a2); a2 = dot2bf(W2.z, i2, a2); a2 = dot2bf(W2.w, i3, a2);
    a3 = dot2bf(W3.x, i0, a3); a3 = dot2bf(W3.y, i1, a3); a3 = dot2bf(W3.z, i2, a3); a3 = dot2bf(W3.w, i3, a3);
  }
  if (kh == 1) { part[jslot][0][b] = a0; part[jslot][1][b] = a1; part[jslot][2][b] = a2; part[jslot][3][b] = a3; }
  __syncthreads();
  if (kh == 0) {
    int xid = E_idx[b * 257 + t];
    const unsigned short* xg = (const unsigned short*)(wsb + OFF_XDEC) + (size_t)xid * 2048;
    float g0 = a0 + part[jslot][0][b] + db[j] + bf2f(xg[j]);
    float g1 = a1 + part[jslot][1][b] + db[512 + j] + bf2f(xg[512 + j]);
    float g2 = a2 + part[jslot][2][b] + db[1024 + j] + bf2f(xg[1024 + j]);
    float g3 = a3 + part[jslot][3][b] + db[1536 + j] + bf2f(xg[1536 + j]);
    float ig = sigm(g0), fg = sigm(g1), gg = tanhf(g2), og = sigm(g3);
    float* cp = (float*)(wsb + OFF_CDEC) + (size_t)j * 128 + b;
    float c = fg * (*cp) + ig * gg;
    *cp = c;
    float h = og * tanhf(c);
    ((unsigned short*)(wsb + OFF_HDEC))[(((size_t)np * 256 + (j >> 1)) * 128 + b) * 2 + (j & 1)] = f2bf(h);
  }
}

// ======================= K2: u = Wattn^T h (grid 256 x 512) =======================
__global__ __launch_bounds__(512) void k_u(char* __restrict__ wsb, int t) {
  int tau = threadIdx.x;
  int b = tau & 127, slot = tau >> 7;
  int i = __builtin_amdgcn_readfirstlane(blockIdx.x * 4 + slot);
  int np = (t & 1) ^ 1;
  const unsigned* inw = (const unsigned*)(wsb + OFF_HDEC) + (size_t)np * 32768 + b;
  const uint4* w = (const uint4*)((const unsigned*)(wsb + OFF_WATTT) + (size_t)i * 256);
  float a = 0.f;
#pragma unroll 4
  for (int q = 0; q < 64; ++q) {
    uint4 W = w[q];
    a = dot2bf(W.x, inw[(q * 4 + 0) * 128], a);
    a = dot2bf(W.y, inw[(q * 4 + 1) * 128], a);
    a = dot2bf(W.z, inw[(q * 4 + 2) * 128], a);
    a = dot2bf(W.w, inw[(q * 4 + 3) * 128], a);
  }
  ((unsigned short*)(wsb + OFF_UFB))[(((size_t)(i >> 1)) * 128 + b) * 2 + (i & 1)] = f2bf(a);
}

// ======================= K3: flash attn chunk (grid 256 x 512, round-5 body) ================
__global__ __launch_bounds__(512) void k_attn(const unsigned char* __restrict__ C_pad,
                                              char* __restrict__ wsb) {
  __shared__ __align__(16) uint4 tile4[8192];   // 64 rows x 1024 bf16 = 128 KiB
  __shared__ __align__(16) unsigned ulds[512];
  __shared__ float sc_l[64];
  __shared__ float p_l[64];
  __shared__ float red[4];
  const unsigned* tl = (const unsigned*)tile4;
  int bid = blockIdx.x, tau = threadIdx.x;
  int b = bid >> 1, ch = bid & 1;
  int lane = tau & 63, wv = tau >> 6;
  const unsigned* UW = (const unsigned*)(wsb + OFF_UFB) + b;
  ulds[tau] = UW[(size_t)tau * 128];
  float mold = -3.0e38f, ssum = 0.f, acc0 = 0.f, acc1 = 0.f;
  unsigned short* SCp = (unsigned short*)(wsb + OFF_SC) + (size_t)b * 256;
  int L0 = ch * 128;
  for (int sub = 0; sub < 2; ++sub) {
    const uint4* src = (const uint4*)((const unsigned short*)wsb + ((size_t)b * 256 + L0 + sub * 64) * 1024);
    __syncthreads();
#pragma unroll
    for (int it = 0; it < 16; ++it) tile4[it * 512 + tau] = src[it * 512 + tau];
    __syncthreads();
    const uint4* u4 = (const uint4*)ulds;
    uint4 ua = u4[lane * 2], ub = u4[lane * 2 + 1];
#pragma unroll
    for (int li = 0; li < 8; ++li) {
      int l = wv * 8 + li;
      uint4 ea = tile4[l * 128 + lane * 2];
      uint4 eb = tile4[l * 128 + lane * 2 + 1];
      float s = 0.f;
      s = dot2bf(ea.x, ua.x, s); s = dot2bf(ea.y, ua.y, s);
      s = dot2bf(ea.z, ua.z, s); s = dot2bf(ea.w, ua.w, s);
      s = dot2bf(eb.x, ub.x, s); s = dot2bf(eb.y, ub.y, s);
      s = dot2bf(eb.z, ub.z, s); s = dot2bf(eb.w, ub.w, s);
      for (int o = 32; o; o >>= 1) s += __shfl_xor(s, o);
      if (lane == 0) {
        int gl = L0 + sub * 64 + l;
        if (C_pad[b * 256 + gl]) s = -3.0e38f;
        sc_l[l] = s;
        SCp[gl] = f2bf(s);
      }
    }
    __syncthreads();
    if (tau < 64) {
      float v = sc_l[tau];
      for (int o = 32; o; o >>= 1) v = fmaxf(v, __shfl_xor(v, o));
      if (tau == 0) red[0] = v;
    }
    __syncthreads();
    float mnew = fmaxf(mold, red[0]);
    float r = expf(mold - mnew);
    if (tau < 64) {
      float pv = expf(sc_l[tau] - mnew);
      p_l[tau] = pv;
      for (int o = 32; o; o >>= 1) pv += __shfl_xor(pv, o);
      if (tau == 0) red[1] = pv;
    }
    __syncthreads();
    ssum = ssum * r + red[1];
    mold = mnew;
    acc0 *= r; acc1 *= r;
#pragma unroll 8
    for (int l = 0; l < 64; ++l) {
      float pv = p_l[l];
      unsigned ev = tl[l * 512 + tau];
      acc0 += pv * bfl(ev); acc1 += pv * bfh(ev);
    }
  }
  ((unsigned*)(wsb + OFF_CTXP))[((size_t)ch * 128 + b) * 512 + tau] =
      (unsigned)f2bf(acc0) | ((unsigned)f2bf(acc1) << 16);
  if (tau == 0) {
    float* MSP = (float*)(wsb + OFF_MSP);
    MSP[b * 2 + ch] = mold;
    MSP[256 + b * 2 + ch] = ssum;
  }
}

// ======================= K4: wout (blocks 0-255) + pgen (blocks 256-383) ====================
__global__ __launch_bounds__(512) void k_wpg(const int* __restrict__ E_idx,
                                             const float* __restrict__ pgc,
                                             const float* __restrict__ pgi,
                                             const float* __restrict__ pgh,
                                             const float* __restrict__ pgcc,
                                             const float* __restrict__ pgb,
                                             char* __restrict__ wsb, int t) {
  __shared__ float part[2][128];
  __shared__ float red[8];
  int tau = threadIdx.x;
  int lane = tau & 63, wv = tau >> 6;
  int rp = t & 1, np = rp ^ 1;
  if (blockIdx.x >= 256) {
    // ---- pgen for b = blockIdx.x - 256 ----
    int b = blockIdx.x - 256;
    const float* MSP = (const float*)(wsb + OFF_MSP);
    float m0 = MSP[b * 2], m1 = MSP[b * 2 + 1];
    float s0 = MSP[256 + b * 2], s1 = MSP[256 + b * 2 + 1];
    float M = fmaxf(m0, m1);
    float e0 = expf(m0 - M), e1 = expf(m1 - M);
    float D = s0 * e0 + s1 * e1;
    float invD = 1.f / D;
    const unsigned* CP0 = (const unsigned*)(wsb + OFF_CTXP) + (size_t)b * 512;
    const unsigned* CP1 = CP0 + 65536;
    unsigned c0 = CP0[tau], c1 = CP1[tau];
    float x0 = (bfl(c0) * e0 + bfl(c1) * e1) * invD;
    float x1 = (bfh(c0) * e0 + bfh(c1) * e1) * invD;
    float pp = x0 * pgc[2 * tau] + x1 * pgc[2 * tau + 1];
    {
      int f = tau;
      const unsigned short* H = (const unsigned short*)(wsb + OFF_HDEC) + (size_t)np * 65536;
      const unsigned short* TOp = (const unsigned short*)(wsb + OFF_TOUT) + (size_t)rp * 65536;
      const float* C = (const float*)(wsb + OFF_CDEC);
      float hv = bf2f(H[((size_t)(f >> 1) * 128 + b) * 2 + (f & 1)]);
      float tv = bf2f(TOp[((size_t)(f >> 1) * 128 + b) * 2 + (f & 1)]);
      float cv = C[(size_t)f * 128 + b];
      pp += hv * pgh[f] + cv * pgcc[f] + tv * pgi[128 + f];
    }
    for (int o = 32; o; o >>= 1) pp += __shfl_xor(pp, o);
    if (lane == 0) red[wv] = pp;
    __syncthreads();
    if (tau == 0) {
      float s = red[0] + red[1] + red[2] + red[3] + red[4] + red[5] + red[6] + red[7];
      s += pgi[E_idx[b * 257 + t]] + pgb[0];
      float* MD = (float*)(wsb + OFF_MD);
      MD[b] = M;
      MD[128 + b] = D;
      MD[256 + b] = sigm(s);
    }
    return;
  }
  // ---- wout with on-the-fly chunk combine (round-5 body) ----
  int b = tau & 127, nslot = (tau >> 7) & 1, kh = tau >> 8;
  int n = __builtin_amdgcn_readfirstlane(blockIdx.x * 2 + nslot);
  const float* MSP = (const float*)(wsb + OFF_MSP);
  float m0 = MSP[b * 2], m1 = MSP[b * 2 + 1];
  float s0 = MSP[256 + b * 2], s1 = MSP[256 + b * 2 + 1];
  float M = fmaxf(m0, m1);
  float e0 = expf(m0 - M), e1 = expf(m1 - M);
  float invD = 1.f / (s0 * e0 + s1 * e1);
  e0 *= invD; e1 *= invD;
  const unsigned* HW = (const unsigned*)(wsb + OFF_HDEC) + (size_t)np * 32768 + b;
  const unsigned* CP0 = (const unsigned*)(wsb + OFF_CTXP) + (size_t)b * 512;
  const unsigned* CP1 = CP0 + 65536;
  const unsigned* w = (const unsigned*)(wsb + OFF_WOUT) + (size_t)n * 768 + kh * 384;
  float a = 0.f;
  int p0 = kh * 384;
#pragma unroll 4
  for (int q = 0; q < 96; ++q) {
    uint4 W = ((const uint4*)w)[q];
#pragma unroll
    for (int e = 0; e < 4; ++e) {
      int pp = p0 + q * 4 + e;
      unsigned wvv = (e == 0) ? W.x : (e == 1) ? W.y : (e == 2) ? W.z : W.w;
      if (pp < 256) {
        a = dot2bf(wvv, HW[(size_t)pp * 128], a);
      } else {
        int ci = pp - 256;
        unsigned c0 = CP0[ci], c1 = CP1[ci];
        float x0 = bfl(c0) * e0 + bfl(c1) * e1;
        float x1 = bfh(c0) * e0 + bfh(c1) * e1;
        a += bfl(wvv) * x0 + bfh(wvv) * x1;
      }
    }
  }
  if (kh == 1) part[nslot][b] = a;
  __syncthreads();
  if (kh == 0) {
    float tv = tanhf(a + part[nslot][b]);
    ((unsigned short*)(wsb + OFF_TOUT))[(((size_t)np * 256 + (n >> 1)) * 128 + b) * 2 + (n & 1)] = f2bf(tv);
  }
}

// ======================= final fin (t=255) =======================
__global__ __launch_bounds__(512) void k_fin_last(const int* __restrict__ C_idx,
                                                  const int* __restrict__ E_idx,
                                                  char* __restrict__ wsb,
                                                  float* __restrict__ out) {
  fin_body(C_idx, E_idx, wsb, out, blockIdx.x, 255);
}

// ======================= host =======================
extern "C" void kernel_launch(void* const* d_in, const int* in_sizes, int n_in,
                              void* d_out, int out_size, void* d_ws, size_t ws_size,
                              hipStream_t stream) {
  (void)in_sizes; (void)n_in; (void)out_size; (void)ws_size;
  const int* C_idx = (const int*)d_in[0];
  const int* E_idx = (const int*)d_in[1];
  const unsigned char* C_pad = (const unsigned char*)d_in[2];
  const float* eWihF = (const float*)d_in[3];
  const float* eWhhF = (const float*)d_in[4];
  const float* ebF   = (const float*)d_in[5];
  const float* eWihB = (const float*)d_in[6];
  const float* eWhhB = (const float*)d_in[7];
  const float* ebB   = (const float*)d_in[8];
  const float* dWih  = (const float*)d_in[9];
  const float* dWhh  = (const float*)d_in[10];
  const float* db    = (const float*)d_in[11];
  const float* Wh    = (const float*)d_in[12];
  const float* Wc    = (const float*)d_in[13];
  const float* Wattn = (const float*)d_in[14];
  const float* Wout  = (const float*)d_in[15];
  const float* Wvoc  = (const float*)d_in[16];
  const float* pgc   = (const float*)d_in[17];
  const float* pgi   = (const float*)d_in[18];
  const float* pgh   = (const float*)d_in[19];
  const float* pgcc  = (const float*)d_in[20];
  const float* pgb   = (const float*)d_in[21];
  char* wsb = (char*)d_ws;
  float* out = (float*)d_out;

  k_pre1<<<256, 256, 0, stream>>>(eWhhF, eWhhB, eWihF, eWihB, wsb);
  k_enc<<<256, 512, 0, stream>>>(ebF, ebB, C_idx, wsb);
  k_h0<<<256, 512, 0, stream>>>(Wh, Wc, wsb);
  // TOUT overlays HFIN -> zero only after h0 consumed HFIN
  hipMemsetAsync(wsb + OFF_TOUT, 0, 524288, stream);
  k_pre2<<<256, 256, 0, stream>>>(dWih, dWhh, Wattn, Wout, Wvoc, wsb);
  for (int t = 0; t < 256; ++t) {
    k_gfin<<<384, 512, 0, stream>>>(C_idx, E_idx, db, wsb, out, t);
    k_u<<<256, 512, 0, stream>>>(wsb, t);
    k_attn<<<256, 512, 0, stream>>>(C_pad, wsb);
    k_wpg<<<384, 512, 0, stream>>>(E_idx, pgc, pgi, pgh, pgcc, pgb, wsb, t);
  }
  k_fin_last<<<128, 512, 0, stream>>>(C_idx, E_idx, wsb, out);
}

// Round 7
// 28244.913 us; speedup vs baseline: 3.3552x; 2.4714x over previous
//
#include <hip/hip_runtime.h>

// ======================= ws layout (bytes) — round-4 layout, unchanged =======================
static constexpr size_t OFF_ENC   = 0;          // bf16 [128 b][256 l][1024 f] = 64 MiB
// ---- enc-phase overlay (round-3 packing) ----
static constexpr size_t OFF_WGE   = 67108864;   // WHHE [2dir][256 k2][512 j][8]  (4 MiB)
static constexpr size_t OFF_WIHTE = 71303168;   // WIHT [2dir][128 v][512 j][4]   (1 MiB)
static constexpr size_t OFF_HENC  = 72351744;   // bf16 paired [(dir*2+par)][256 kk][128 b] (512 KiB)
static constexpr size_t OFF_CENC  = 72876032;   // f32  [2dir][512][128]          (512 KiB)
// ---- dec-phase overlay ----
static constexpr size_t OFF_WGATE = 67108864;   // bf16 [2048 row][1024 k]        (4 MiB)
static constexpr size_t OFF_XDEC  = 71303168;   // bf16 [128 v][2048 row]         (512 KiB)
static constexpr size_t OFF_WATTT = 71827456;   // bf16 [1024 i][512 o]           (1 MiB)
static constexpr size_t OFF_WOUT  = 72876032;   // bf16 [512 n][1536 k]           (1.5 MiB)
static constexpr size_t OFF_WVOCT = 74448896;   // u32  [256 kk][128 v] bf16x2    (128 KiB)
// ---- persistent dec state ----
static constexpr size_t OFF_HDEC  = 74579968;   // bf16 paired [2 par][256 kk][128 b]
static constexpr size_t OFF_CDEC  = 74842112;   // f32 [512][128]  (single plane RMW)
static constexpr size_t OFF_TOUT  = 75104256;   // bf16 paired [2 par][256 kk][128 b]
static constexpr size_t OFF_UFB   = 75366400;   // bf16 paired [512 kk][128 b]
static constexpr size_t OFF_CTXF  = 75628544;   // bf16 paired [512 kk][128 b]
static constexpr size_t OFF_CTXP  = 75890688;   // u32 [2 ch][128 b][512]
static constexpr size_t OFF_SC    = 76414976;   // bf16 [128 b][256 l]
static constexpr size_t OFF_MSP   = 76480512;   // f32 m[128][2]; s[128][2] at +1024
static constexpr size_t OFF_MD    = 76482560;   // f32 M[128], D[128], PG[128]

// ======================= helpers =======================
__device__ __forceinline__ float sigm(float x) { return 1.f / (1.f + expf(-x)); }
__device__ __forceinline__ unsigned short f2bf(float f) {
  unsigned u = __float_as_uint(f);
  u += 0x7fffu + ((u >> 16) & 1u);
  return (unsigned short)(u >> 16);
}
__device__ __forceinline__ float bfl(unsigned w) { return __uint_as_float(w << 16); }
__device__ __forceinline__ float bfh(unsigned w) { return __uint_as_float(w & 0xffff0000u); }
__device__ __forceinline__ float bf2f(unsigned short v) { return __uint_as_float(((unsigned)v) << 16); }

#if defined(__has_builtin)
#if __has_builtin(__builtin_amdgcn_fdot2_f32_bf16)
#define HAVE_DOT2BF 1
#endif
#endif
#ifdef HAVE_DOT2BF
typedef __bf16 bf2_t __attribute__((ext_vector_type(2)));
__device__ __forceinline__ float dot2bf(unsigned w, unsigned h, float acc) {
  return __builtin_amdgcn_fdot2_f32_bf16(__builtin_bit_cast(bf2_t, w),
                                         __builtin_bit_cast(bf2_t, h), acc, false);
}
#else
__device__ __forceinline__ float dot2bf(unsigned w, unsigned h, float acc) {
  return acc + bfl(w) * bfl(h) + bfh(w) * bfh(h);
}
#endif

// ======================= pre1: encoder weight packing (round-3 layout, proven) ==============
__global__ __launch_bounds__(256) void k_pre1(const float* __restrict__ WhhF,
                                              const float* __restrict__ WhhB,
                                              const float* __restrict__ WihF,
                                              const float* __restrict__ WihB,
                                              char* __restrict__ wsb) {
  unsigned short* dst = (unsigned short*)(wsb + OFF_WGE);
  int id = blockIdx.x * 256 + threadIdx.x, str = gridDim.x * 256;
  for (int x = id; x < 2097152; x += str) {           // WHHE [dir][k2][j][8], e=g*2+kk
    int dir = x >> 20, r = x & 1048575;
    int e = r & 7, j = (r >> 3) & 511, k2 = r >> 12;
    int g = e >> 1, k = k2 * 2 + (e & 1);
    const float* W = dir ? WhhB : WhhF;
    dst[x] = f2bf(W[((size_t)g * 512 + j) * 512 + k]);
  }
  for (int x = id; x < 524288; x += str) {            // WIHT [dir][v][j][4]
    int dir = x >> 18, r = x & 262143;
    int g = r & 3, j = (r >> 2) & 511, v = r >> 11;
    const float* W = dir ? WihB : WihF;
    dst[2097152 + x] = f2bf(W[((size_t)g * 512 + j) * 128 + v]);
  }
}

// ======================= encoder: one block per (b, dir), all 256 steps (round-3, proven) ====
__global__ __launch_bounds__(512) void k_enc(const float* __restrict__ bF,
                                             const float* __restrict__ bB,
                                             const int* __restrict__ C_idx,
                                             char* __restrict__ wsb) {
  __shared__ __align__(16) unsigned short hbf[512];
  int bid = blockIdx.x;
  int b = bid & 127, dir = bid >> 7;
  int j = threadIdx.x;
  const unsigned short* WH = (const unsigned short*)(wsb + OFF_WGE) + (size_t)dir * 1048576;
  const unsigned short* WX = (const unsigned short*)(wsb + OFF_WGE) + 2097152 + (size_t)dir * 262144;
  const float* bias = dir ? bB : bF;
  float b0 = bias[j], b1 = bias[512 + j], b2 = bias[1024 + j], b3 = bias[1536 + j];
  unsigned short* encb = (unsigned short*)wsb + (size_t)b * 262144;
  const uint4* wp = (const uint4*)WH + j;
  float c = 0.f, h = 0.f;
  hbf[j] = 0;
  __syncthreads();
  for (int t = 0; t < 256; ++t) {
    int l = dir ? (255 - t) : t;
    int cidx = C_idx[b * 256 + l];
    uint2 xg = *(const uint2*)(WX + ((size_t)cidx * 512 + j) * 4);
    float a0 = b0 + bfl(xg.x), a1 = b1 + bfh(xg.x);
    float a2 = b2 + bfl(xg.y), a3 = b3 + bfh(xg.y);
    for (int k2 = 0; k2 < 256; ++k2) {
      uint4 w = wp[(size_t)k2 * 512];
      unsigned hp = *(const unsigned*)((const char*)hbf + k2 * 4);
      a0 = dot2bf(w.x, hp, a0);
      a1 = dot2bf(w.y, hp, a1);
      a2 = dot2bf(w.z, hp, a2);
      a3 = dot2bf(w.w, hp, a3);
    }
    float ig = sigm(a0), fg = sigm(a1), gg = tanhf(a2), og = sigm(a3);
    c = fg * c + ig * gg;
    h = og * tanhf(c);
    __syncthreads();
    unsigned short hb = f2bf(h);
    hbf[j] = hb;
    encb[(size_t)l * 1024 + dir * 512 + j] = hb;
    __syncthreads();
  }
  // finals in round-4 formats so k_h0 is unchanged
  ((unsigned short*)(wsb + OFF_HENC))[(((size_t)(dir * 2 + 0) * 256 + (j >> 1)) * 128 + b) * 2 + (j & 1)] = f2bf(h);
  ((float*)(wsb + OFF_CENC))[((size_t)dir * 512 + j) * 128 + b] = c;
}

// ======================= h0/c0 (round-4, unchanged) =======================
__global__ __launch_bounds__(512) void k_h0(const float* __restrict__ Wh,
                                            const float* __restrict__ Wc,
                                            char* __restrict__ wsb) {
  int tau = threadIdx.x;
  int b = tau & 127, slot = tau >> 7;
  int row = __builtin_amdgcn_readfirstlane(blockIdx.x * 4 + slot);
  int sel = row >> 9, j = row & 511;
  const float* W = (sel ? Wc : Wh) + (size_t)j * 1024;
  const unsigned short* HE = (const unsigned short*)(wsb + OFF_HENC);
  const float* CE = (const float*)(wsb + OFF_CENC);
  float acc = 0.f;
  for (int k = 0; k < 1024; ++k) {
    int dir = k >> 9, k5 = k & 511;
    float in;
    if (sel == 0)
      in = bf2f(HE[(((size_t)(dir * 2 + 0) * 256 + (k5 >> 1)) * 128 + b) * 2 + (k5 & 1)]);
    else
      in = CE[((size_t)dir * 512 + k5) * 128 + b];
    acc += W[k] * in;
  }
  if (sel == 0)
    ((unsigned short*)(wsb + OFF_HDEC))[(((size_t)(j >> 1)) * 128 + b) * 2 + (j & 1)] = f2bf(acc);
  else
    ((float*)(wsb + OFF_CDEC))[(size_t)j * 128 + b] = acc;
}

// ======================= pre2: decoder weight packing (round-4, unchanged) ==================
__global__ __launch_bounds__(256) void k_pre2(const float* __restrict__ dWih,
                                              const float* __restrict__ dWhh,
                                              const float* __restrict__ Wattn,
                                              const float* __restrict__ Wout,
                                              const float* __restrict__ Wvoc,
                                              char* __restrict__ wsb) {
  unsigned short* WG = (unsigned short*)(wsb + OFF_WGATE);
  unsigned short* XD = (unsigned short*)(wsb + OFF_XDEC);
  unsigned short* WA = (unsigned short*)(wsb + OFF_WATTT);
  unsigned short* WO = (unsigned short*)(wsb + OFF_WOUT);
  unsigned*       WV = (unsigned*)(wsb + OFF_WVOCT);
  int id = blockIdx.x * 256 + threadIdx.x, str = gridDim.x * 256;
  for (int x = id; x < 2048 * 1024; x += str) {
    int r = x >> 10, k = x & 1023;
    float v = (k < 512) ? dWih[(size_t)r * 640 + 128 + k] : dWhh[(size_t)r * 512 + (k - 512)];
    WG[x] = f2bf(v);
  }
  for (int x = id; x < 128 * 2048; x += str) {
    int v = x >> 11, r = x & 2047;
    XD[x] = f2bf(dWih[(size_t)r * 640 + v]);
  }
  for (int x = id; x < 1024 * 512; x += str) {
    int i = x >> 9, o = x & 511;
    WA[x] = f2bf(Wattn[(size_t)o * 1024 + i]);
  }
  for (int x = id; x < 512 * 1536; x += str) WO[x] = f2bf(Wout[x]);
  for (int x = id; x < 256 * 128; x += str) {
    int kk = x >> 7, v = x & 127;
    unsigned lo = f2bf(Wvoc[(size_t)v * 512 + 2 * kk]);
    unsigned hi = f2bf(Wvoc[(size_t)v * 512 + 2 * kk + 1]);
    WV[x] = lo | (hi << 16);
  }
}

// ======================= K1: gates (round-4, unchanged) =======================
__global__ __launch_bounds__(512) void k_gates(const int* __restrict__ E_idx,
                                               const float* __restrict__ db,
                                               char* __restrict__ wsb, int t) {
  __shared__ float part[2][4][128];
  int tau = threadIdx.x;
  int b = tau & 127, jslot = (tau >> 7) & 1, kh = tau >> 8;
  int j = __builtin_amdgcn_readfirstlane(blockIdx.x * 2 + jslot);
  int rp = t & 1, np = rp ^ 1;
  const unsigned* inw = (const unsigned*)(wsb + (kh ? OFF_HDEC : OFF_TOUT)) + (size_t)rp * 32768 + b;
  const unsigned* WG = (const unsigned*)(wsb + OFF_WGATE);
  const uint4* w0 = (const uint4*)(WG + (size_t)j * 512 + kh * 256);
  const uint4* w1 = (const uint4*)(WG + ((size_t)512 + j) * 512 + kh * 256);
  const uint4* w2 = (const uint4*)(WG + ((size_t)1024 + j) * 512 + kh * 256);
  const uint4* w3 = (const uint4*)(WG + ((size_t)1536 + j) * 512 + kh * 256);
  float a0 = 0.f, a1 = 0.f, a2 = 0.f, a3 = 0.f;
#pragma unroll 4
  for (int q = 0; q < 64; ++q) {
    uint4 W0 = w0[q], W1 = w1[q], W2 = w2[q], W3 = w3[q];
    unsigned i0 = inw[(q * 4 + 0) * 128], i1 = inw[(q * 4 + 1) * 128];
    unsigned i2 = inw[(q * 4 + 2) * 128], i3 = inw[(q * 4 + 3) * 128];
    a0 = dot2bf(W0.x, i0, a0); a0 = dot2bf(W0.y, i1, a0); a0 = dot2bf(W0.z, i2, a0); a0 = dot2bf(W0.w, i3, a0);
    a1 = dot2bf(W1.x, i0, a1); a1 = dot2bf(W1.y, i1, a1); a1 = dot2bf(W1.z, i2, a1); a1 = dot2bf(W1.w, i3, a1);
    a2 = dot2bf(W2.x, i0, a2); a2 = dot2bf(W2.y, i1, a2); a2 = dot2bf(W2.z, i2, a2); a2 = dot2bf(W2.w, i3, a2);
    a3 = dot2bf(W3.x, i0, a3); a3 = dot2bf(W3.y, i1, a3); a3 = dot2bf(W3.z, i2, a3); a3 = dot2bf(W3.w, i3, a3);
  }
  if (kh == 1) { part[jslot][0][b] = a0; part[jslot][1][b] = a1; part[jslot][2][b] = a2; part[jslot][3][b] = a3; }
  __syncthreads();
  if (kh == 0) {
    int xid = E_idx[b * 257 + t];
    const unsigned short* xg = (const unsigned short*)(wsb + OFF_XDEC) + (size_t)xid * 2048;
    float g0 = a0 + part[jslot][0][b] + db[j] + bf2f(xg[j]);
    float g1 = a1 + part[jslot][1][b] + db[512 + j] + bf2f(xg[512 + j]);
    float g2 = a2 + part[jslot][2][b] + db[1024 + j] + bf2f(xg[1024 + j]);
    float g3 = a3 + part[jslot][3][b] + db[1536 + j] + bf2f(xg[1536 + j]);
    float ig = sigm(g0), fg = sigm(g1), gg = tanhf(g2), og = sigm(g3);
    float* cp = (float*)(wsb + OFF_CDEC) + (size_t)j * 128 + b;
    float c = fg * (*cp) + ig * gg;
    *cp = c;
    float h = og * tanhf(c);
    ((unsigned short*)(wsb + OFF_HDEC))[(((size_t)np * 256 + (j >> 1)) * 128 + b) * 2 + (j & 1)] = f2bf(h);
  }
}

// ======================= K2: u = Wattn^T h (round-4, unchanged) =======================
__global__ __launch_bounds__(512) void k_u(char* __restrict__ wsb, int t) {
  int tau = threadIdx.x;
  int b = tau & 127, slot = tau >> 7;
  int i = __builtin_amdgcn_readfirstlane(blockIdx.x * 4 + slot);
  int np = (t & 1) ^ 1;
  const unsigned* inw = (const unsigned*)(wsb + OFF_HDEC) + (size_t)np * 32768 + b;
  const uint4* w = (const uint4*)((const unsigned*)(wsb + OFF_WATTT) + (size_t)i * 256);
  float a = 0.f;
#pragma unroll 4
  for (int q = 0; q < 64; ++q) {
    uint4 W = w[q];
    a = dot2bf(W.x, inw[(q * 4 + 0) * 128], a);
    a = dot2bf(W.y, inw[(q * 4 + 1) * 128], a);
    a = dot2bf(W.z, inw[(q * 4 + 2) * 128], a);
    a = dot2bf(W.w, inw[(q * 4 + 3) * 128], a);
  }
  ((unsigned short*)(wsb + OFF_UFB))[(((size_t)(i >> 1)) * 128 + b) * 2 + (i & 1)] = f2bf(a);
}

// ======================= K3: flash attn chunk (round-4 256-thread version, unchanged) =======
__global__ __launch_bounds__(256) void k_attn(const unsigned char* __restrict__ C_pad,
                                              char* __restrict__ wsb) {
  __shared__ __align__(16) unsigned short tile[32][1024];  // 64 KiB
  __shared__ __align__(16) unsigned ulds[512];
  __shared__ float sc_l[32];
  __shared__ float p_l[32];
  __shared__ float red[4];
  int bid = blockIdx.x, tau = threadIdx.x;
  int b = bid >> 1, ch = bid & 1;
  int lane = tau & 63, wv = tau >> 6;
  const unsigned* UW = (const unsigned*)(wsb + OFF_UFB) + b;
  ulds[tau] = UW[(size_t)tau * 128];
  ulds[tau + 256] = UW[(size_t)(tau + 256) * 128];
  float mold = -3.0e38f, ssum = 0.f;
  float acc0 = 0.f, acc1 = 0.f, acc2 = 0.f, acc3 = 0.f;
  unsigned short* SCp = (unsigned short*)(wsb + OFF_SC) + (size_t)b * 256;
  int L0 = ch * 128;
  for (int sub = 0; sub < 4; ++sub) {
    const uint4* src = (const uint4*)((const unsigned short*)wsb + ((size_t)b * 256 + L0 + sub * 32) * 1024);
    __syncthreads();
#pragma unroll
    for (int it = 0; it < 16; ++it) ((uint4*)tile)[it * 256 + tau] = src[it * 256 + tau];
    __syncthreads();
    const uint4* t4 = (const uint4*)tile;
    const uint4* u4 = (const uint4*)ulds;
#pragma unroll
    for (int li = 0; li < 8; ++li) {
      int l = wv * 8 + li;
      uint4 ea = t4[l * 128 + lane * 2];
      uint4 eb = t4[l * 128 + lane * 2 + 1];
      uint4 ua = u4[lane * 2];
      uint4 ub = u4[lane * 2 + 1];
      float s = 0.f;
      s = dot2bf(ea.x, ua.x, s); s = dot2bf(ea.y, ua.y, s);
      s = dot2bf(ea.z, ua.z, s); s = dot2bf(ea.w, ua.w, s);
      s = dot2bf(eb.x, ub.x, s); s = dot2bf(eb.y, ub.y, s);
      s = dot2bf(eb.z, ub.z, s); s = dot2bf(eb.w, ub.w, s);
      for (int o = 32; o; o >>= 1) s += __shfl_xor(s, o);
      if (lane == 0) {
        int gl = L0 + sub * 32 + l;
        if (C_pad[b * 256 + gl]) s = -3.0e38f;
        sc_l[l] = s;
        SCp[gl] = f2bf(s);
      }
    }
    __syncthreads();
    if (tau < 64) {
      float v = (tau < 32) ? sc_l[tau] : -3.0e38f;
      for (int o = 32; o; o >>= 1) v = fmaxf(v, __shfl_xor(v, o));
      if (tau == 0) red[0] = v;
    }
    __syncthreads();
    float mnew = fmaxf(mold, red[0]);
    float r = expf(mold - mnew);
    if (tau < 64) {
      float pv = (tau < 32) ? expf(sc_l[tau] - mnew) : 0.f;
      if (tau < 32) p_l[tau] = pv;
      for (int o = 32; o; o >>= 1) pv += __shfl_xor(pv, o);
      if (tau == 0) red[1] = pv;
    }
    __syncthreads();
    ssum = ssum * r + red[1];
    mold = mnew;
    acc0 *= r; acc1 *= r; acc2 *= r; acc3 *= r;
    const uint2* t2 = (const uint2*)tile;
#pragma unroll 8
    for (int l = 0; l < 32; ++l) {
      float pv = p_l[l];
      uint2 ev = t2[l * 256 + tau];
      acc0 += pv * bfl(ev.x); acc1 += pv * bfh(ev.x);
      acc2 += pv * bfl(ev.y); acc3 += pv * bfh(ev.y);
    }
  }
  unsigned* CP = (unsigned*)(wsb + OFF_CTXP);
  unsigned wlo = (unsigned)f2bf(acc0) | ((unsigned)f2bf(acc1) << 16);
  unsigned whi = (unsigned)f2bf(acc2) | ((unsigned)f2bf(acc3) << 16);
  CP[(((size_t)ch * 128 + b) * 1024 + tau * 4) >> 1] = wlo;
  CP[((((size_t)ch * 128 + b) * 1024 + tau * 4) >> 1) + 1] = whi;
  if (tau == 0) {
    float* MSP = (float*)(wsb + OFF_MSP);
    MSP[b * 2 + ch] = mold;
    MSP[256 + b * 2 + ch] = ssum;
  }
}

// ======================= K4: combine + pgen (round-4, unchanged) =======================
__global__ __launch_bounds__(256) void k_comb(const int* __restrict__ E_idx,
                                              const float* __restrict__ pgc,
                                              const float* __restrict__ pgi,
                                              const float* __restrict__ pgh,
                                              const float* __restrict__ pgcc,
                                              const float* __restrict__ pgb,
                                              char* __restrict__ wsb, int t) {
  __shared__ float red[4];
  int b = blockIdx.x, tau = threadIdx.x;
  int lane = tau & 63, wv = tau >> 6;
  int rp = t & 1, np = rp ^ 1;
  const float* MSP = (const float*)(wsb + OFF_MSP);
  float m0 = MSP[b * 2], m1 = MSP[b * 2 + 1];
  float s0 = MSP[256 + b * 2], s1 = MSP[256 + b * 2 + 1];
  float M = fmaxf(m0, m1);
  float e0 = expf(m0 - M), e1 = expf(m1 - M);
  float D = s0 * e0 + s1 * e1;
  float invD = 1.f / D;
  const unsigned* CP = (const unsigned*)(wsb + OFF_CTXP);
  size_t base0 = (((size_t)0 * 128 + b) * 1024 + tau * 4) >> 1;
  size_t base1 = (((size_t)1 * 128 + b) * 1024 + tau * 4) >> 1;
  unsigned c0l = CP[base0], c0h = CP[base0 + 1], c1l = CP[base1], c1h = CP[base1 + 1];
  float x0 = (bfl(c0l) * e0 + bfl(c1l) * e1) * invD;
  float x1 = (bfh(c0l) * e0 + bfh(c1l) * e1) * invD;
  float x2 = (bfl(c0h) * e0 + bfl(c1h) * e1) * invD;
  float x3 = (bfh(c0h) * e0 + bfh(c1h) * e1) * invD;
  unsigned* CF = (unsigned*)(wsb + OFF_CTXF);
  CF[((size_t)tau * 2) * 128 + b]     = (unsigned)f2bf(x0) | ((unsigned)f2bf(x1) << 16);
  CF[((size_t)tau * 2 + 1) * 128 + b] = (unsigned)f2bf(x2) | ((unsigned)f2bf(x3) << 16);
  int f0 = tau * 4;
  float pp = x0 * pgc[f0] + x1 * pgc[f0 + 1] + x2 * pgc[f0 + 2] + x3 * pgc[f0 + 3];
  if (f0 < 512) {
    const unsigned short* H = (const unsigned short*)(wsb + OFF_HDEC);
    const unsigned short* TO = (const unsigned short*)(wsb + OFF_TOUT);
    const float* C = (const float*)(wsb + OFF_CDEC);
#pragma unroll
    for (int e = 0; e < 4; ++e) {
      int f = f0 + e;
      float hv = bf2f(H[(((size_t)np * 256 + (f >> 1)) * 128 + b) * 2 + (f & 1)]);
      float pv = bf2f(TO[(((size_t)rp * 256 + (f >> 1)) * 128 + b) * 2 + (f & 1)]);
      float cv = C[(size_t)f * 128 + b];
      pp += hv * pgh[f] + cv * pgcc[f] + pv * pgi[128 + f];
    }
  }
  for (int o = 32; o; o >>= 1) pp += __shfl_xor(pp, o);
  if (lane == 0) red[wv] = pp;
  __syncthreads();
  if (tau == 0) {
    int xid = E_idx[b * 257 + t];
    float s = red[0] + red[1] + red[2] + red[3] + pgi[xid] + pgb[0];
    float* MD = (float*)(wsb + OFF_MD);
    MD[b] = M;
    MD[128 + b] = D;
    MD[256 + b] = sigm(s);
  }
}

// ======================= K5: wout (round-4, unchanged) =======================
__global__ __launch_bounds__(512) void k_wout(char* __restrict__ wsb, int t) {
  __shared__ float part[2][128];
  int tau = threadIdx.x;
  int b = tau & 127, nslot = (tau >> 7) & 1, kh = tau >> 8;
  int n = __builtin_amdgcn_readfirstlane(blockIdx.x * 2 + nslot);
  int np = (t & 1) ^ 1;
  const unsigned* HW = (const unsigned*)(wsb + OFF_HDEC) + (size_t)np * 32768 + b;
  const unsigned* CW = (const unsigned*)(wsb + OFF_CTXF) + b;
  const unsigned* w = (const unsigned*)(wsb + OFF_WOUT) + (size_t)n * 768 + kh * 384;
  float a = 0.f;
  int p0 = kh * 384;
#pragma unroll 4
  for (int q = 0; q < 96; ++q) {
    uint4 W = ((const uint4*)w)[q];
#pragma unroll
    for (int e = 0; e < 4; ++e) {
      int pp = p0 + q * 4 + e;
      unsigned in = (pp < 256) ? HW[(size_t)pp * 128] : CW[(size_t)(pp - 256) * 128];
      unsigned wv = (e == 0) ? W.x : (e == 1) ? W.y : (e == 2) ? W.z : W.w;
      a = dot2bf(wv, in, a);
    }
  }
  if (kh == 1) part[nslot][b] = a;
  __syncthreads();
  if (kh == 0) {
    float tv = tanhf(a + part[nslot][b]);
    ((unsigned short*)(wsb + OFF_TOUT))[(((size_t)np * 256 + (n >> 1)) * 128 + b) * 2 + (n & 1)] = f2bf(tv);
  }
}

// ======================= K6: vocab softmax + copy mass + nll (round-4, unchanged) ===========
__global__ __launch_bounds__(256) void k_fin(const int* __restrict__ C_idx,
                                             const int* __restrict__ E_idx,
                                             char* __restrict__ wsb,
                                             float* __restrict__ out, int t) {
  __shared__ unsigned to_pld[256];
  __shared__ float lgp[2][128];
  __shared__ float lgf[128];
  __shared__ float red[8];
  int b = blockIdx.x, tau = threadIdx.x;
  int lane = tau & 63, wv = tau >> 6;
  int np = (t & 1) ^ 1;
  const unsigned* TOW = (const unsigned*)(wsb + OFF_TOUT) + (size_t)np * 32768 + b;
  to_pld[tau] = TOW[(size_t)tau * 128];
  __syncthreads();
  int v = tau & 127, kh = tau >> 7;
  const unsigned* WV = (const unsigned*)(wsb + OFF_WVOCT) + v;
  float a = 0.f;
#pragma unroll 8
  for (int kkk = 0; kkk < 128; ++kkk) {
    int kk = kh * 128 + kkk;
    a = dot2bf(WV[(size_t)kk * 128], to_pld[kk], a);
  }
  lgp[kh][v] = a;
  __syncthreads();
  if (tau < 128) {
    float lg = lgp[0][tau] + lgp[1][tau];
    lgf[tau] = lg;
    float m = lg;
    for (int o = 32; o; o >>= 1) m = fmaxf(m, __shfl_xor(m, o));
    if (lane == 0) red[wv] = m;
  }
  __syncthreads();
  float mx = fmaxf(red[0], red[1]);
  if (tau < 128) {
    float e = expf(lgf[tau] - mx);
    for (int o = 32; o; o >>= 1) e += __shfl_xor(e, o);
    if (lane == 0) red[2 + wv] = e;
  }
  __syncthreads();
  const float* MD = (const float*)(wsb + OFF_MD);
  float M = MD[b], D = MD[128 + b], pg = MD[256 + b];
  int tgt = E_idx[b * 257 + t + 1];
  float cm = 0.f;
  {
    float s = bf2f(((const unsigned short*)(wsb + OFF_SC))[(size_t)b * 256 + tau]);
    if (C_idx[b * 256 + tau] == tgt) cm = expf(s - M);
  }
  for (int o = 32; o; o >>= 1) cm += __shfl_xor(cm, o);
  if (lane == 0) red[4 + wv] = cm;
  __syncthreads();
  if (tau == 0) {
    float sume = red[2] + red[3];
    float copy_raw = red[4] + red[5] + red[6] + red[7];
    float gen_tgt = expf(lgf[tgt] - mx) / sume;
    float prob = pg * gen_tgt + (1.f - pg) * copy_raw / D;
    out[b * 256 + t] = (tgt == 0) ? 0.f : -logf(prob);
  }
}

// ======================= host =======================
extern "C" void kernel_launch(void* const* d_in, const int* in_sizes, int n_in,
                              void* d_out, int out_size, void* d_ws, size_t ws_size,
                              hipStream_t stream) {
  (void)in_sizes; (void)n_in; (void)out_size; (void)ws_size;
  const int* C_idx = (const int*)d_in[0];
  const int* E_idx = (const int*)d_in[1];
  const unsigned char* C_pad = (const unsigned char*)d_in[2];
  const float* eWihF = (const float*)d_in[3];
  const float* eWhhF = (const float*)d_in[4];
  const float* ebF   = (const float*)d_in[5];
  const float* eWihB = (const float*)d_in[6];
  const float* eWhhB = (const float*)d_in[7];
  const float* ebB   = (const float*)d_in[8];
  const float* dWih  = (const float*)d_in[9];
  const float* dWhh  = (const float*)d_in[10];
  const float* db    = (const float*)d_in[11];
  const float* Wh    = (const float*)d_in[12];
  const float* Wc    = (const float*)d_in[13];
  const float* Wattn = (const float*)d_in[14];
  const float* Wout  = (const float*)d_in[15];
  const float* Wvoc  = (const float*)d_in[16];
  const float* pgc   = (const float*)d_in[17];
  const float* pgi   = (const float*)d_in[18];
  const float* pgh   = (const float*)d_in[19];
  const float* pgcc  = (const float*)d_in[20];
  const float* pgb   = (const float*)d_in[21];
  char* wsb = (char*)d_ws;
  float* out = (float*)d_out;

  hipMemsetAsync(wsb + OFF_TOUT, 0, 262144, stream);   // prev_out both parities

  k_pre1<<<256, 256, 0, stream>>>(eWhhF, eWhhB, eWihF, eWihB, wsb);
  k_enc<<<256, 512, 0, stream>>>(ebF, ebB, C_idx, wsb);
  k_h0<<<256, 512, 0, stream>>>(Wh, Wc, wsb);
  k_pre2<<<256, 256, 0, stream>>>(dWih, dWhh, Wattn, Wout, Wvoc, wsb);
  for (int t = 0; t < 256; ++t) {
    k_gates<<<256, 512, 0, stream>>>(E_idx, db, wsb, t);
    k_u<<<256, 512, 0, stream>>>(wsb, t);
    k_attn<<<256, 256, 0, stream>>>(C_pad, wsb);
    k_comb<<<128, 256, 0, stream>>>(E_idx, pgc, pgi, pgh, pgcc, pgb, wsb, t);
    k_wout<<<256, 512, 0, stream>>>(wsb, t);
    k_fin<<<128, 256, 0, stream>>>(C_idx, E_idx, wsb, out, t);
  }
}